// Round 12
// baseline (312.425 us; speedup 1.0000x reference)
//
#include <hip/hip_runtime.h>
#include <hip/hip_bf16.h>

#define B_ 4
#define T_ 2048
#define C_ 1024
#define H_ 16
#define HD_ 64
#define M_ (B_*T_)   // 8192

typedef __attribute__((ext_vector_type(8))) short short8;
typedef __attribute__((ext_vector_type(4))) float f32x4;
typedef __attribute__((ext_vector_type(16))) float f32x16;
typedef __attribute__((ext_vector_type(4))) unsigned int u32x4;
typedef unsigned short u16;
typedef unsigned int u32;

__device__ __forceinline__ u16 f2bf(float f){
  unsigned int x = __builtin_bit_cast(unsigned int, f);
  x += 0x7fffu + ((x >> 16) & 1u);   // RNE
  return (u16)(x >> 16);
}

__device__ __forceinline__ float b2f(u16 u){
  u32 x = ((u32)u) << 16;
  return __builtin_bit_cast(float, x);
}

__device__ __forceinline__ u32 cvtpk(float lo, float hi){
  u32 r;
  asm("v_cvt_pk_bf16_f32 %0, %1, %2" : "=v"(r) : "v"(lo), "v"(hi));
  return r;
}

// async global->LDS, 16B per lane; LDS dest must be wave-uniform base + lane*16
#define GLOAD_LDS(gsrc, ldst) \
  __builtin_amdgcn_global_load_lds((const __attribute__((address_space(1))) u32*)(gsrc), \
                                   (__attribute__((address_space(3))) u32*)(ldst), 16, 0, 0)

// ---------------- fp32 -> bf16 convert ----------------
__global__ __launch_bounds__(256) void cvt_kernel(const float* __restrict__ in,
                                                  u16* __restrict__ out, int n4){
  int i = blockIdx.x * 256 + threadIdx.x;
  if (i >= n4) return;
  float4 f = reinterpret_cast<const float4*>(in)[i];
  ushort4 u;
  u.x = f2bf(f.x); u.y = f2bf(f.y); u.z = f2bf(f.z); u.w = f2bf(f.w);
  reinterpret_cast<ushort4*>(out)[i] = u;
}

// ---------------- GEMM: C[M,N] = A[M,K] * Bt[N,K]^T + bias ----------------
// m97-structure: linear [128][64] LDS tiles staged via global_load_lds width=16.
// MODE 0: scatter-epilogue into q/k/v [B,H,T,HD] bf16 (Q pre-scaled by 0.125*log2e).
// MODE 1: fp32 row-major out.
template<int MODE>
__global__ __launch_bounds__(256)
void gemm_bt(const u16* __restrict__ A, const u16* __restrict__ Bt,
             const float* __restrict__ bias, float* __restrict__ Cf,
             u16* __restrict__ Qo, u16* __restrict__ Ko, u16* __restrict__ Vo,
             int N, int K)
{
  __shared__ u16 As[128 * 64];   // linear, unpadded (gload_lds requirement)
  __shared__ u16 Bs[128 * 64];
  const int tid = threadIdx.x;
  const int wave = tid >> 6, lane = tid & 63;
  const int lo = lane & 15, hi = lane >> 4;
  const int wm = (wave >> 1) * 64, wn = (wave & 1) * 64;
  const long bm = (long)blockIdx.y * 128, bn = (long)blockIdx.x * 128;

  f32x4 acc[4][4];
  #pragma unroll
  for (int i = 0; i < 4; i++)
    #pragma unroll
    for (int j = 0; j < 4; j++)
      acc[i][j] = (f32x4){0.f, 0.f, 0.f, 0.f};

  for (int k0 = 0; k0 < K; k0 += 64){
    if (k0) __syncthreads();
    #pragma unroll
    for (int j = 0; j < 4; j++){
      int chunk = j * 256 + tid;
      int row = chunk >> 3, cc = (chunk & 7) * 8;
      GLOAD_LDS(&A [(bm + row) * K + k0 + cc], &As[chunk * 8]);
      GLOAD_LDS(&Bt[(bn + row) * K + k0 + cc], &Bs[chunk * 8]);
    }
    __syncthreads();
    #pragma unroll
    for (int kk = 0; kk < 64; kk += 32){
      short8 af[4], bf[4];
      #pragma unroll
      for (int mi = 0; mi < 4; mi++)
        af[mi] = *reinterpret_cast<const short8*>(&As[(wm + mi*16 + lo) * 64 + kk + hi*8]);
      #pragma unroll
      for (int ni = 0; ni < 4; ni++)
        bf[ni] = *reinterpret_cast<const short8*>(&Bs[(wn + ni*16 + lo) * 64 + kk + hi*8]);
      #pragma unroll
      for (int mi = 0; mi < 4; mi++)
        #pragma unroll
        for (int ni = 0; ni < 4; ni++)
          acc[mi][ni] = __builtin_amdgcn_mfma_f32_16x16x32_bf16(af[mi], bf[ni], acc[mi][ni], 0, 0, 0);
    }
  }

  #pragma unroll
  for (int mi = 0; mi < 4; mi++){
    #pragma unroll
    for (int ni = 0; ni < 4; ni++){
      #pragma unroll
      for (int rg = 0; rg < 4; rg++){
        long rowg = bm + wm + mi*16 + hi*4 + rg;
        long colg = bn + wn + ni*16 + lo;
        float v = acc[mi][ni][rg] + bias[colg];
        if (MODE == 0){
          int part = (int)(colg >> 10), cc = (int)(colg & 1023);
          int h = cc >> 6, d = cc & 63;
          long b = rowg >> 11, t = rowg & 2047;
          if (part == 0) v *= 0.18033688f;   // 0.125 * log2(e): S lands in exp2 domain
          u16* dst = (part == 0) ? Qo : ((part == 1) ? Ko : Vo);
          dst[(((b << 4) + h) * 2048 + t) * 64 + d] = f2bf(v);
        } else {
          Cf[rowg * (long)N + colg] = v;
        }
      }
    }
  }
}

// ---------------- V transpose: [bh][t][d] -> [bh][d][t] ----------------
__global__ __launch_bounds__(256)
void vtrans_kernel(const u16* __restrict__ V, u16* __restrict__ Vt){
  __shared__ u16 Ls[64][72];
  const int bh = blockIdx.y;
  const int t0 = blockIdx.x * 64;
  const u16* Vb = V + ((size_t)bh * 2048 + t0) * 64;
  u16* Ob = Vt + (size_t)bh * 64 * 2048 + t0;
  const int r = threadIdx.x >> 3;        // 0..31
  const int c = (threadIdx.x & 7) * 8;   // 0..56
  #pragma unroll
  for (int rr = 0; rr < 64; rr += 32){
    int row = r + rr;
    *reinterpret_cast<short8*>(&Ls[row][c ^ (((row >> 4) & 3) << 4)]) =
      *reinterpret_cast<const short8*>(&Vb[(size_t)row * 64 + c]);
  }
  __syncthreads();
  const int d  = threadIdx.x >> 2;       // 0..63
  const int tc = (threadIdx.x & 3) * 16; // 0,16,32,48
  const int v  = ((tc >> 4) & 3) << 4;
  short8 o0, o1;
  #pragma unroll
  for (int j = 0; j < 8; j++) o0[j] = (short)Ls[tc + j][d ^ v];
  #pragma unroll
  for (int j = 0; j < 8; j++) o1[j] = (short)Ls[tc + 8 + j][d ^ v];
  *reinterpret_cast<short8*>(&Ob[(size_t)d * 2048 + tc]) = o0;
  *reinterpret_cast<short8*>(&Ob[(size_t)d * 2048 + tc + 8]) = o1;
}

// ---------------- causal flash attention with kv-split ----------------
// Per-tile body = R10 verbatim (swapped 32x32 MFMA, in-reg softmax, T12 pack,
// setprio). Schedule: 3072 blocks x 128 thr (2 waves). Mapping (approx LPT):
//   u = blk>>6; u<32: SPLIT qc = 63-u, wave=half (kv range halved);
//   u>=32: UNSPLIT v = 47-u, qc = 2v+wave (equal-F pair, R6-proven).
// Split waves write unnormalized partials (O bf16 -> Opart, m/l fp32 -> Ml);
// combine_kernel merges. No LDS, no barriers, no votes.
__global__ __launch_bounds__(128, 4)
void attn_kernel(const u16* __restrict__ Q, const u16* __restrict__ K,
                 const u16* __restrict__ Vt, u16* __restrict__ Y,
                 u16* __restrict__ Opart, float* __restrict__ Ml)
{
  const int blk = blockIdx.x;            // 0..3071
  const int bh = (blk & 7) * 8 + ((blk >> 3) & 7);  // 8 bh per XCD
  const int u = blk >> 6;                // 0..47
  const int tid = threadIdx.x, wave = tid >> 6, lane = tid & 63;
  const int l31 = lane & 31, h5 = lane >> 5;

  int qc, jt0, jt1, half;
  bool split;
  if (u < 32){                           // long rows, kv-split in two
    split = true;
    qc = 63 - u;                         // 63..32 (longest first)
    half = wave;
    int nt = (qc >> 1) + 1;              // 17..32 tiles
    int h0 = (nt + 1) >> 1;
    jt0 = half ? h0 : 0;
    jt1 = half ? nt : h0;
  } else {                               // short rows, unsplit, equal-F pairs
    split = false;
    int v = 47 - u;                      // 15..0
    qc = 2 * v + wave;
    half = 0;
    jt0 = 0;
    jt1 = (qc >> 1) + 1;
  }
  const int F = qc >> 1;                 // diagonal tile index
  const int q0w = qc * 32;
  const int qrow = q0w + l31;            // this lane's q row
  const u16* Qb = Q  + (size_t)bh * 2048 * 64;
  const u16* Kb = K  + (size_t)bh * 2048 * 64;
  const u16* Vb = Vt + (size_t)bh * 64 * 2048;

  // Q^T B-frags: col=q=lane&31, k(d) = ks*16 + h5*8 + j
  short8 qf[4];
  #pragma unroll
  for (int ks = 0; ks < 4; ks++)
    qf[ks] = *reinterpret_cast<const short8*>(&Qb[(size_t)qrow * 64 + ks * 16 + h5 * 8]);

  f32x16 o0, o1;
  #pragma unroll
  for (int i = 0; i < 16; i++){ o0[i] = 0.f; o1[i] = 0.f; }
  float m = -1e30f, l = 0.f;

  for (int jt = jt0; jt < jt1; jt++){
    const int k0 = jt << 6;

    // ---- K A-frags: row=kv(lane&31), k(d)=ks*16+h5*8+j ; 2 kv-blocks of 32 ----
    short8 kf0[4], kf1[4];
    #pragma unroll
    for (int ks = 0; ks < 4; ks++){
      kf0[ks] = *reinterpret_cast<const short8*>(&Kb[(size_t)(k0 + l31) * 64 + ks * 16 + h5 * 8]);
      kf1[ks] = *reinterpret_cast<const short8*>(&Kb[(size_t)(k0 + 32 + l31) * 64 + ks * 16 + h5 * 8]);
    }
    // ---- S^T = K . Q^T : col=q, row=kv=(r&3)+8*(r>>2)+4*h5 (+32*n) ----
    f32x16 st0, st1;
    #pragma unroll
    for (int i = 0; i < 16; i++){ st0[i] = 0.f; st1[i] = 0.f; }
    __builtin_amdgcn_s_setprio(1);
    #pragma unroll
    for (int ks = 0; ks < 4; ks++)
      st0 = __builtin_amdgcn_mfma_f32_32x32x16_bf16(kf0[ks], qf[ks], st0, 0, 0, 0);
    #pragma unroll
    for (int ks = 0; ks < 4; ks++)
      st1 = __builtin_amdgcn_mfma_f32_32x32x16_bf16(kf1[ks], qf[ks], st1, 0, 0, 0);
    __builtin_amdgcn_s_setprio(0);

    // ---- V^T A-frags: row=d, k(kv)=ks*16+h5*8+j ----
    short8 vf0[4], vf1[4];
    #pragma unroll
    for (int ks = 0; ks < 4; ks++){
      vf0[ks] = *reinterpret_cast<const short8*>(&Vb[(size_t)l31 * 2048 + k0 + ks * 16 + h5 * 8]);
      vf1[ks] = *reinterpret_cast<const short8*>(&Vb[(size_t)(32 + l31) * 2048 + k0 + ks * 16 + h5 * 8]);
    }

    // ---- causal mask (diagonal tile only; only its owner wave reaches it) ----
    if (jt == F){
      #pragma unroll
      for (int r = 0; r < 16; r++){
        int kvr = k0 + (r & 3) + 8 * (r >> 2) + 4 * h5;
        if (kvr > qrow)      st0[r] = -1e30f;
        if (kvr + 32 > qrow) st1[r] = -1e30f;
      }
    }

    // ---- in-register online softmax (one q-row per lane), rescale every tile ----
    float t[16];
    #pragma unroll
    for (int r = 0; r < 16; r++) t[r] = fmaxf(st0[r], st1[r]);
    #pragma unroll
    for (int s = 8; s > 0; s >>= 1)
      #pragma unroll
      for (int r = 0; r < 8; r++) if (r < s) t[r] = fmaxf(t[r], t[r + s]);
    float rm = fmaxf(t[0], __shfl_xor(t[0], 32));
    float mn = fmaxf(m, rm);
    float alpha = __builtin_amdgcn_exp2f(m - mn);
    m = mn;
    float rs = 0.f;
    #pragma unroll
    for (int r = 0; r < 16; r++){
      st0[r] = __builtin_amdgcn_exp2f(st0[r] - mn);
      st1[r] = __builtin_amdgcn_exp2f(st1[r] - mn);
      rs += st0[r] + st1[r];
    }
    rs += __shfl_xor(rs, 32);
    l = l * alpha + rs;
    #pragma unroll
    for (int i = 0; i < 16; i++){ o0[i] *= alpha; o1[i] *= alpha; }

    // ---- pack P^T B-frags: pa[ks2][e] = P[q][ks2*16 + h5*8 + e] (T12 exchange) ----
    short8 pa[4];
    #pragma unroll
    for (int ks2 = 0; ks2 < 4; ks2++){
      const f32x16& sv = (ks2 < 2) ? st0 : st1;
      const int gg = 8 * (ks2 & 1);
      u32 w0 = cvtpk(sv[gg + 0], sv[gg + 1]);
      u32 w1 = cvtpk(sv[gg + 2], sv[gg + 3]);
      u32 w2 = cvtpk(sv[gg + 4], sv[gg + 5]);
      u32 w3 = cvtpk(sv[gg + 6], sv[gg + 7]);
      u32 sa = h5 ? w0 : w2;               // send partner what it needs
      u32 sb = h5 ? w1 : w3;
      u32 ra = (u32)__shfl_xor((int)sa, 32);
      u32 rb = (u32)__shfl_xor((int)sb, 32);
      u32x4 pw;
      pw.x = h5 ? ra : w0;
      pw.y = h5 ? rb : w1;
      pw.z = h5 ? w2 : ra;
      pw.w = h5 ? w3 : rb;
      pa[ks2] = __builtin_bit_cast(short8, pw);
    }

    // ---- O^T += V^T . P^T ----
    __builtin_amdgcn_s_setprio(1);
    #pragma unroll
    for (int ks = 0; ks < 4; ks++)
      o0 = __builtin_amdgcn_mfma_f32_32x32x16_bf16(vf0[ks], pa[ks], o0, 0, 0, 0);
    #pragma unroll
    for (int ks = 0; ks < 4; ks++)
      o1 = __builtin_amdgcn_mfma_f32_32x32x16_bf16(vf1[ks], pa[ks], o1, 0, 0, 0);
    __builtin_amdgcn_s_setprio(0);
  }

  // ---- epilogue ----
  if (!split){
    // normalize and write Y directly (R10 verbatim)
    const int b = bh >> 4, h = bh & 15;
    const float inv = 1.f / l;
    u16* Yr = Y + ((size_t)(b * 2048 + qrow)) * 1024 + h * 64;
    #pragma unroll
    for (int rq = 0; rq < 4; rq++){
      ushort4 ua, ub;
      #pragma unroll
      for (int e = 0; e < 4; e++){
        ((u16*)&ua)[e] = f2bf(o0[rq * 4 + e] * inv);
        ((u16*)&ub)[e] = f2bf(o1[rq * 4 + e] * inv);
      }
      *reinterpret_cast<ushort4*>(&Yr[rq * 8 + h5 * 4])      = ua;
      *reinterpret_cast<ushort4*>(&Yr[32 + rq * 8 + h5 * 4]) = ub;
    }
  } else {
    // write unnormalized partial: Opart[unit][row=l31][64 d] bf16, Ml[unit][row][{m,l}]
    const int unit = (bh * 32 + (qc - 32)) * 2 + half;
    u16* Or = Opart + (size_t)unit * 2048 + l31 * 64;
    #pragma unroll
    for (int rq = 0; rq < 4; rq++){
      ushort4 ua, ub;
      #pragma unroll
      for (int e = 0; e < 4; e++){
        ((u16*)&ua)[e] = f2bf(o0[rq * 4 + e]);
        ((u16*)&ub)[e] = f2bf(o1[rq * 4 + e]);
      }
      *reinterpret_cast<ushort4*>(&Or[rq * 8 + h5 * 4])      = ua;
      *reinterpret_cast<ushort4*>(&Or[32 + rq * 8 + h5 * 4]) = ub;
    }
    if (h5 == 0){                        // lanes 0..31 hold the 32 rows' (m,l)
      Ml[(size_t)unit * 64 + l31 * 2 + 0] = m;
      Ml[(size_t)unit * 64 + l31 * 2 + 1] = l;
    }
  }
}

// ---------------- combine: merge the two kv-halves of each long row ----------------
// grid 2048 blocks (bh*32+qcrel) x 256 thr: t -> row r=t>>3, d8=(t&7)*8.
__global__ __launch_bounds__(256)
void combine_kernel(const u16* __restrict__ Opart, const float* __restrict__ Ml,
                    u16* __restrict__ Y)
{
  const int cb = blockIdx.x;             // 0..2047
  const int bh = cb >> 5, qcrel = cb & 31;
  const int t = threadIdx.x;
  const int r = t >> 3, d8 = (t & 7) * 8;
  const int u0 = (bh * 32 + qcrel) * 2, u1 = u0 + 1;

  float m0 = Ml[(size_t)u0 * 64 + r * 2], l0 = Ml[(size_t)u0 * 64 + r * 2 + 1];
  float m1 = Ml[(size_t)u1 * 64 + r * 2], l1 = Ml[(size_t)u1 * 64 + r * 2 + 1];
  float mS = fmaxf(m0, m1);
  float a0 = __builtin_amdgcn_exp2f(m0 - mS);
  float a1 = __builtin_amdgcn_exp2f(m1 - mS);
  float inv = 1.f / (l0 * a0 + l1 * a1);

  short8 O0 = *reinterpret_cast<const short8*>(&Opart[(size_t)u0 * 2048 + r * 64 + d8]);
  short8 O1 = *reinterpret_cast<const short8*>(&Opart[(size_t)u1 * 2048 + r * 64 + d8]);
  ushort4 oa, ob;
  #pragma unroll
  for (int j = 0; j < 8; j++){
    float y = (b2f((u16)O0[j]) * a0 + b2f((u16)O1[j]) * a1) * inv;
    ((u16*)(j < 4 ? &oa : &ob))[j & 3] = f2bf(y);
  }
  const int qc = 32 + qcrel;
  const int qrow = qc * 32 + r;
  const int b = bh >> 4, h = bh & 15;
  u16* Yr = Y + ((size_t)(b * 2048 + qrow)) * 1024 + h * 64 + d8;
  *reinterpret_cast<ushort4*>(Yr)     = oa;
  *reinterpret_cast<ushort4*>(Yr + 4) = ob;
}

// ---------------- launch ----------------
extern "C" void kernel_launch(void* const* d_in, const int* in_sizes, int n_in,
                              void* d_out, int out_size, void* d_ws, size_t ws_size,
                              hipStream_t stream)
{
  const float* x      = (const float*)d_in[0];
  const float* w_qkv  = (const float*)d_in[1];
  const float* b_qkv  = (const float*)d_in[2];
  const float* w_proj = (const float*)d_in[3];
  const float* b_proj = (const float*)d_in[4];
  float* out = (float*)d_out;

  char* ws = (char*)d_ws;
  u16* xb     = (u16*)(ws);                       // 16 MB  [8192,1024]  (reused as vtb)
  u16* wqkvb  = (u16*)(ws + (16u << 20));         //  6 MB  [3072,1024]  (reused as Ml)
  u16* wprojb = (u16*)(ws + (22u << 20));         //  2 MB  [1024,1024]
  u16* qb     = (u16*)(ws + (24u << 20));         // 16 MB  [64,2048,64]
  u16* kb     = (u16*)(ws + (40u << 20));         // 16 MB
  u16* vb     = (u16*)(ws + (56u << 20));         // 16 MB  (reused as Opart)
  u16* yb     = (u16*)(ws + (72u << 20));         // 16 MB  [8192,1024]
  u16* vtb    = xb;                               // [64,64,2048] (after GEMM1, xb dead)
  u16* opart  = vb;                               // 16 MB partials (after vtrans, vb dead)
  float* ml   = (float*)wqkvb;                    //  1 MB m/l     (after GEMM1, wqkvb dead)

  int nx  = B_ * T_ * C_ / 4;         // 2097152
  int nw1 = 3 * C_ * C_ / 4;          //  786432
  int nw2 = C_ * C_ / 4;              //  262144
  cvt_kernel<<<(nx  + 255) / 256, 256, 0, stream>>>(x,      xb,     nx);
  cvt_kernel<<<(nw1 + 255) / 256, 256, 0, stream>>>(w_qkv,  wqkvb,  nw1);
  cvt_kernel<<<(nw2 + 255) / 256, 256, 0, stream>>>(w_proj, wprojb, nw2);

  dim3 g1(3072 / 128, M_ / 128);
  gemm_bt<0><<<g1, 256, 0, stream>>>(xb, wqkvb, b_qkv, nullptr, qb, kb, vb, 3072, C_);

  dim3 gt(T_ / 64, B_ * H_);
  vtrans_kernel<<<gt, 256, 0, stream>>>(vb, vtb);

  attn_kernel<<<3072, 128, 0, stream>>>(qb, kb, vtb, yb, opart, ml);
  combine_kernel<<<2048, 256, 0, stream>>>(opart, ml, yb);

  dim3 g2(1024 / 128, M_ / 128);
  gemm_bt<1><<<g2, 256, 0, stream>>>(yb, wprojb, b_proj, out, nullptr, nullptr, nullptr, C_, C_);
}

// Round 13
// 283.225 us; speedup vs baseline: 1.1031x; 1.1031x over previous
//
#include <hip/hip_runtime.h>
#include <hip/hip_bf16.h>

#define B_ 4
#define T_ 2048
#define C_ 1024
#define H_ 16
#define HD_ 64
#define M_ (B_*T_)   // 8192

typedef __attribute__((ext_vector_type(8))) short short8;
typedef __attribute__((ext_vector_type(4))) float f32x4;
typedef __attribute__((ext_vector_type(16))) float f32x16;
typedef __attribute__((ext_vector_type(4))) unsigned int u32x4;
typedef unsigned short u16;
typedef unsigned int u32;

__device__ __forceinline__ u16 f2bf(float f){
  unsigned int x = __builtin_bit_cast(unsigned int, f);
  x += 0x7fffu + ((x >> 16) & 1u);   // RNE
  return (u16)(x >> 16);
}

__device__ __forceinline__ u32 cvtpk(float lo, float hi){
  u32 r;
  asm("v_cvt_pk_bf16_f32 %0, %1, %2" : "=v"(r) : "v"(lo), "v"(hi));
  return r;
}

// async global->LDS, 16B per lane; LDS dest must be wave-uniform base + lane*16
#define GLOAD_LDS(gsrc, ldst) \
  __builtin_amdgcn_global_load_lds((const __attribute__((address_space(1))) u32*)(gsrc), \
                                   (__attribute__((address_space(3))) u32*)(ldst), 16, 0, 0)

// ---------------- fp32 -> bf16 convert ----------------
__global__ __launch_bounds__(256) void cvt_kernel(const float* __restrict__ in,
                                                  u16* __restrict__ out, int n4){
  int i = blockIdx.x * 256 + threadIdx.x;
  if (i >= n4) return;
  float4 f = reinterpret_cast<const float4*>(in)[i];
  ushort4 u;
  u.x = f2bf(f.x); u.y = f2bf(f.y); u.z = f2bf(f.z); u.w = f2bf(f.w);
  reinterpret_cast<ushort4*>(out)[i] = u;
}

// ---------------- GEMM: C[M,N] = A[M,K] * Bt[N,K]^T + bias ----------------
// m97-structure: linear [128][64] LDS tiles staged via global_load_lds width=16.
// MODE 0: scatter-epilogue into q/k/v [B,H,T,HD] bf16 (Q pre-scaled by 0.125*log2e).
// MODE 1: fp32 row-major out.
template<int MODE>
__global__ __launch_bounds__(256)
void gemm_bt(const u16* __restrict__ A, const u16* __restrict__ Bt,
             const float* __restrict__ bias, float* __restrict__ Cf,
             u16* __restrict__ Qo, u16* __restrict__ Ko, u16* __restrict__ Vo,
             int N, int K)
{
  __shared__ u16 As[128 * 64];   // linear, unpadded (gload_lds requirement)
  __shared__ u16 Bs[128 * 64];
  const int tid = threadIdx.x;
  const int wave = tid >> 6, lane = tid & 63;
  const int lo = lane & 15, hi = lane >> 4;
  const int wm = (wave >> 1) * 64, wn = (wave & 1) * 64;
  const long bm = (long)blockIdx.y * 128, bn = (long)blockIdx.x * 128;

  f32x4 acc[4][4];
  #pragma unroll
  for (int i = 0; i < 4; i++)
    #pragma unroll
    for (int j = 0; j < 4; j++)
      acc[i][j] = (f32x4){0.f, 0.f, 0.f, 0.f};

  for (int k0 = 0; k0 < K; k0 += 64){
    if (k0) __syncthreads();
    #pragma unroll
    for (int j = 0; j < 4; j++){
      int chunk = j * 256 + tid;
      int row = chunk >> 3, cc = (chunk & 7) * 8;
      GLOAD_LDS(&A [(bm + row) * K + k0 + cc], &As[chunk * 8]);
      GLOAD_LDS(&Bt[(bn + row) * K + k0 + cc], &Bs[chunk * 8]);
    }
    __syncthreads();
    #pragma unroll
    for (int kk = 0; kk < 64; kk += 32){
      short8 af[4], bf[4];
      #pragma unroll
      for (int mi = 0; mi < 4; mi++)
        af[mi] = *reinterpret_cast<const short8*>(&As[(wm + mi*16 + lo) * 64 + kk + hi*8]);
      #pragma unroll
      for (int ni = 0; ni < 4; ni++)
        bf[ni] = *reinterpret_cast<const short8*>(&Bs[(wn + ni*16 + lo) * 64 + kk + hi*8]);
      #pragma unroll
      for (int mi = 0; mi < 4; mi++)
        #pragma unroll
        for (int ni = 0; ni < 4; ni++)
          acc[mi][ni] = __builtin_amdgcn_mfma_f32_16x16x32_bf16(af[mi], bf[ni], acc[mi][ni], 0, 0, 0);
    }
  }

  #pragma unroll
  for (int mi = 0; mi < 4; mi++){
    #pragma unroll
    for (int ni = 0; ni < 4; ni++){
      #pragma unroll
      for (int rg = 0; rg < 4; rg++){
        long rowg = bm + wm + mi*16 + hi*4 + rg;
        long colg = bn + wn + ni*16 + lo;
        float v = acc[mi][ni][rg] + bias[colg];
        if (MODE == 0){
          int part = (int)(colg >> 10), cc = (int)(colg & 1023);
          int h = cc >> 6, d = cc & 63;
          long b = rowg >> 11, t = rowg & 2047;
          if (part == 0) v *= 0.18033688f;   // 0.125 * log2(e): S lands in exp2 domain
          u16* dst = (part == 0) ? Qo : ((part == 1) ? Ko : Vo);
          dst[(((b << 4) + h) * 2048 + t) * 64 + d] = f2bf(v);
        } else {
          Cf[rowg * (long)N + colg] = v;
        }
      }
    }
  }
}

// ---------------- V transpose: [bh][t][d] -> [bh][d][t] ----------------
__global__ __launch_bounds__(256)
void vtrans_kernel(const u16* __restrict__ V, u16* __restrict__ Vt){
  __shared__ u16 Ls[64][72];
  const int bh = blockIdx.y;
  const int t0 = blockIdx.x * 64;
  const u16* Vb = V + ((size_t)bh * 2048 + t0) * 64;
  u16* Ob = Vt + (size_t)bh * 64 * 2048 + t0;
  const int r = threadIdx.x >> 3;        // 0..31
  const int c = (threadIdx.x & 7) * 8;   // 0..56
  #pragma unroll
  for (int rr = 0; rr < 64; rr += 32){
    int row = r + rr;
    *reinterpret_cast<short8*>(&Ls[row][c ^ (((row >> 4) & 3) << 4)]) =
      *reinterpret_cast<const short8*>(&Vb[(size_t)row * 64 + c]);
  }
  __syncthreads();
  const int d  = threadIdx.x >> 2;       // 0..63
  const int tc = (threadIdx.x & 3) * 16; // 0,16,32,48
  const int v  = ((tc >> 4) & 3) << 4;
  short8 o0, o1;
  #pragma unroll
  for (int j = 0; j < 8; j++) o0[j] = (short)Ls[tc + j][d ^ v];
  #pragma unroll
  for (int j = 0; j < 8; j++) o1[j] = (short)Ls[tc + 8 + j][d ^ v];
  *reinterpret_cast<short8*>(&Ob[(size_t)d * 2048 + tc]) = o0;
  *reinterpret_cast<short8*>(&Ob[(size_t)d * 2048 + tc + 8]) = o1;
}

// ---------------- causal flash attention: swapped 32x32 MFMA, in-reg softmax ----
// R10 body verbatim. Schedule: 4096 blocks x 64 threads (ONE wave per block) —
// single-wave granularity backfill; LPT via qc = 63-(blk>>6) (all heads' longest
// rows first); bh mapping unchanged (8 bh per XCD, KV L2-resident).
// Q,K: [64 bh][2048 t][64 d] bf16 (Q pre-scaled by 0.125*log2e).
// Vt: [64 bh][64 d][2048 t].  Y: [B,T,C] bf16 (head-merged).
__global__ __launch_bounds__(64, 4)
void attn_kernel(const u16* __restrict__ Q, const u16* __restrict__ K,
                 const u16* __restrict__ Vt, u16* __restrict__ Y)
{
  const int blk = blockIdx.x;            // 0..4095
  const int bh = (blk & 7) * 8 + ((blk >> 3) & 7);  // 8 bh per XCD (4MB KV in L2)
  const int qc = 63 - (blk >> 6);        // LPT: qc=63 blocks dispatch first
  const int lane = threadIdx.x & 63;
  const int l31 = lane & 31, h5 = lane >> 5;
  const int q0w = qc * 32;
  const int qrow = q0w + l31;            // this lane's q row
  const u16* Qb = Q  + (size_t)bh * 2048 * 64;
  const u16* Kb = K  + (size_t)bh * 2048 * 64;
  const u16* Vb = Vt + (size_t)bh * 64 * 2048;

  // Q^T B-frags: col=q=lane&31, k(d) = ks*16 + h5*8 + j
  short8 qf[4];
  #pragma unroll
  for (int ks = 0; ks < 4; ks++)
    qf[ks] = *reinterpret_cast<const short8*>(&Qb[(size_t)qrow * 64 + ks * 16 + h5 * 8]);

  f32x16 o0, o1;
  #pragma unroll
  for (int i = 0; i < 16; i++){ o0[i] = 0.f; o1[i] = 0.f; }
  float m = -1e30f, l = 0.f;

  const int F = qc >> 1;                 // diagonal tile index

  for (int jt = 0; jt <= F; jt++){
    const int k0 = jt << 6;

    // ---- K A-frags: row=kv(lane&31), k(d)=ks*16+h5*8+j ; 2 kv-blocks of 32 ----
    short8 kf0[4], kf1[4];
    #pragma unroll
    for (int ks = 0; ks < 4; ks++){
      kf0[ks] = *reinterpret_cast<const short8*>(&Kb[(size_t)(k0 + l31) * 64 + ks * 16 + h5 * 8]);
      kf1[ks] = *reinterpret_cast<const short8*>(&Kb[(size_t)(k0 + 32 + l31) * 64 + ks * 16 + h5 * 8]);
    }
    // ---- S^T = K . Q^T : col=q, row=kv=(r&3)+8*(r>>2)+4*h5 (+32*n) ----
    f32x16 st0, st1;
    #pragma unroll
    for (int i = 0; i < 16; i++){ st0[i] = 0.f; st1[i] = 0.f; }
    __builtin_amdgcn_s_setprio(1);
    #pragma unroll
    for (int ks = 0; ks < 4; ks++)
      st0 = __builtin_amdgcn_mfma_f32_32x32x16_bf16(kf0[ks], qf[ks], st0, 0, 0, 0);
    #pragma unroll
    for (int ks = 0; ks < 4; ks++)
      st1 = __builtin_amdgcn_mfma_f32_32x32x16_bf16(kf1[ks], qf[ks], st1, 0, 0, 0);
    __builtin_amdgcn_s_setprio(0);

    // ---- V^T A-frags issued early: row=d, k(kv)=ks*16+h5*8+j ----
    short8 vf0[4], vf1[4];
    #pragma unroll
    for (int ks = 0; ks < 4; ks++){
      vf0[ks] = *reinterpret_cast<const short8*>(&Vb[(size_t)l31 * 2048 + k0 + ks * 16 + h5 * 8]);
      vf1[ks] = *reinterpret_cast<const short8*>(&Vb[(size_t)(32 + l31) * 2048 + k0 + ks * 16 + h5 * 8]);
    }

    // ---- causal mask (diagonal tile only) ----
    if (jt == F){
      #pragma unroll
      for (int r = 0; r < 16; r++){
        int kvr = k0 + (r & 3) + 8 * (r >> 2) + 4 * h5;
        if (kvr > qrow)      st0[r] = -1e30f;
        if (kvr + 32 > qrow) st1[r] = -1e30f;
      }
    }

    // ---- in-register online softmax (one q-row per lane), rescale every tile ----
    float t[16];
    #pragma unroll
    for (int r = 0; r < 16; r++) t[r] = fmaxf(st0[r], st1[r]);
    #pragma unroll
    for (int s = 8; s > 0; s >>= 1)
      #pragma unroll
      for (int r = 0; r < 8; r++) if (r < s) t[r] = fmaxf(t[r], t[r + s]);
    float rm = fmaxf(t[0], __shfl_xor(t[0], 32));
    float mn = fmaxf(m, rm);
    float alpha = __builtin_amdgcn_exp2f(m - mn);
    m = mn;
    float rs = 0.f;
    #pragma unroll
    for (int r = 0; r < 16; r++){
      st0[r] = __builtin_amdgcn_exp2f(st0[r] - mn);
      st1[r] = __builtin_amdgcn_exp2f(st1[r] - mn);
      rs += st0[r] + st1[r];
    }
    rs += __shfl_xor(rs, 32);
    l = l * alpha + rs;
    #pragma unroll
    for (int i = 0; i < 16; i++){ o0[i] *= alpha; o1[i] *= alpha; }

    // ---- pack P^T B-frags: pa[ks2][e] = P[q][ks2*16 + h5*8 + e] (T12 exchange) ----
    short8 pa[4];
    #pragma unroll
    for (int ks2 = 0; ks2 < 4; ks2++){
      const f32x16& sv = (ks2 < 2) ? st0 : st1;
      const int gg = 8 * (ks2 & 1);
      u32 w0 = cvtpk(sv[gg + 0], sv[gg + 1]);
      u32 w1 = cvtpk(sv[gg + 2], sv[gg + 3]);
      u32 w2 = cvtpk(sv[gg + 4], sv[gg + 5]);
      u32 w3 = cvtpk(sv[gg + 6], sv[gg + 7]);
      u32 sa = h5 ? w0 : w2;               // send partner what it needs
      u32 sb = h5 ? w1 : w3;
      u32 ra = (u32)__shfl_xor((int)sa, 32);
      u32 rb = (u32)__shfl_xor((int)sb, 32);
      u32x4 pw;
      pw.x = h5 ? ra : w0;
      pw.y = h5 ? rb : w1;
      pw.z = h5 ? w2 : ra;
      pw.w = h5 ? w3 : rb;
      pa[ks2] = __builtin_bit_cast(short8, pw);
    }

    // ---- O^T += V^T . P^T ----
    __builtin_amdgcn_s_setprio(1);
    #pragma unroll
    for (int ks = 0; ks < 4; ks++)
      o0 = __builtin_amdgcn_mfma_f32_32x32x16_bf16(vf0[ks], pa[ks], o0, 0, 0, 0);
    #pragma unroll
    for (int ks = 0; ks < 4; ks++)
      o1 = __builtin_amdgcn_mfma_f32_32x32x16_bf16(vf1[ks], pa[ks], o1, 0, 0, 0);
    __builtin_amdgcn_s_setprio(0);
  }

  // ---- epilogue: O^T lane holds col q=l31, rows d = (r&3)+8*(r>>2)+4*h5 (+32) ----
  const int b = bh >> 4, h = bh & 15;
  const float inv = 1.f / l;
  u16* Yr = Y + ((size_t)(b * 2048 + qrow)) * 1024 + h * 64;
  #pragma unroll
  for (int rq = 0; rq < 4; rq++){
    ushort4 ua, ub;
    #pragma unroll
    for (int e = 0; e < 4; e++){
      ((u16*)&ua)[e] = f2bf(o0[rq * 4 + e] * inv);
      ((u16*)&ub)[e] = f2bf(o1[rq * 4 + e] * inv);
    }
    *reinterpret_cast<ushort4*>(&Yr[rq * 8 + h5 * 4])      = ua;
    *reinterpret_cast<ushort4*>(&Yr[32 + rq * 8 + h5 * 4]) = ub;
  }
}

// ---------------- launch ----------------
extern "C" void kernel_launch(void* const* d_in, const int* in_sizes, int n_in,
                              void* d_out, int out_size, void* d_ws, size_t ws_size,
                              hipStream_t stream)
{
  const float* x      = (const float*)d_in[0];
  const float* w_qkv  = (const float*)d_in[1];
  const float* b_qkv  = (const float*)d_in[2];
  const float* w_proj = (const float*)d_in[3];
  const float* b_proj = (const float*)d_in[4];
  float* out = (float*)d_out;

  char* ws = (char*)d_ws;
  u16* xb     = (u16*)(ws);                       // 16 MB  [8192,1024]  (reused as vtb)
  u16* wqkvb  = (u16*)(ws + (16u << 20));         //  6 MB  [3072,1024]
  u16* wprojb = (u16*)(ws + (22u << 20));         //  2 MB  [1024,1024]
  u16* qb     = (u16*)(ws + (24u << 20));         // 16 MB  [64,2048,64]
  u16* kb     = (u16*)(ws + (40u << 20));         // 16 MB
  u16* vb     = (u16*)(ws + (56u << 20));         // 16 MB
  u16* yb     = (u16*)(ws + (72u << 20));         // 16 MB  [8192,1024]
  u16* vtb    = xb;                               // 16 MB  [64,64,2048] (after GEMM1, xb is dead)

  int nx  = B_ * T_ * C_ / 4;         // 2097152
  int nw1 = 3 * C_ * C_ / 4;          //  786432
  int nw2 = C_ * C_ / 4;              //  262144
  cvt_kernel<<<(nx  + 255) / 256, 256, 0, stream>>>(x,      xb,     nx);
  cvt_kernel<<<(nw1 + 255) / 256, 256, 0, stream>>>(w_qkv,  wqkvb,  nw1);
  cvt_kernel<<<(nw2 + 255) / 256, 256, 0, stream>>>(w_proj, wprojb, nw2);

  dim3 g1(3072 / 128, M_ / 128);
  gemm_bt<0><<<g1, 256, 0, stream>>>(xb, wqkvb, b_qkv, nullptr, qb, kb, vb, 3072, C_);

  dim3 gt(T_ / 64, B_ * H_);
  vtrans_kernel<<<gt, 256, 0, stream>>>(vb, vtb);

  attn_kernel<<<4096, 64, 0, stream>>>(qb, kb, vtb, yb);

  dim3 g2(1024 / 128, M_ / 128);
  gemm_bt<1><<<g2, 256, 0, stream>>>(yb, wprojb, b_proj, out, nullptr, nullptr, nullptr, C_, C_);
}

// Round 14
// 268.142 us; speedup vs baseline: 1.1651x; 1.0562x over previous
//
#include <hip/hip_runtime.h>
#include <hip/hip_bf16.h>

#define B_ 4
#define T_ 2048
#define C_ 1024
#define H_ 16
#define HD_ 64
#define M_ (B_*T_)   // 8192

typedef __attribute__((ext_vector_type(8))) short short8;
typedef __attribute__((ext_vector_type(4))) float f32x4;
typedef __attribute__((ext_vector_type(16))) float f32x16;
typedef __attribute__((ext_vector_type(4))) unsigned int u32x4;
typedef unsigned short u16;
typedef unsigned int u32;

__device__ __forceinline__ u16 f2bf(float f){
  unsigned int x = __builtin_bit_cast(unsigned int, f);
  x += 0x7fffu + ((x >> 16) & 1u);   // RNE
  return (u16)(x >> 16);
}

__device__ __forceinline__ u32 cvtpk(float lo, float hi){
  u32 r;
  asm("v_cvt_pk_bf16_f32 %0, %1, %2" : "=v"(r) : "v"(lo), "v"(hi));
  return r;
}

// async global->LDS, 16B per lane; LDS dest must be wave-uniform base + lane*16
#define GLOAD_LDS(gsrc, ldst) \
  __builtin_amdgcn_global_load_lds((const __attribute__((address_space(1))) u32*)(gsrc), \
                                   (__attribute__((address_space(3))) u32*)(ldst), 16, 0, 0)

// ---------------- fp32 -> bf16 convert ----------------
__global__ __launch_bounds__(256) void cvt_kernel(const float* __restrict__ in,
                                                  u16* __restrict__ out, int n4){
  int i = blockIdx.x * 256 + threadIdx.x;
  if (i >= n4) return;
  float4 f = reinterpret_cast<const float4*>(in)[i];
  ushort4 u;
  u.x = f2bf(f.x); u.y = f2bf(f.y); u.z = f2bf(f.z); u.w = f2bf(f.w);
  reinterpret_cast<ushort4*>(out)[i] = u;
}

// ---------------- GEMM: C[M,N] = A[M,K] * Bt[N,K]^T + bias ----------------
// m97-structure: linear [128][64] LDS tiles staged via global_load_lds width=16.
// MODE 0: scatter-epilogue into q/k/v [B,H,T,HD] bf16 (Q pre-scaled by 0.125*log2e).
// MODE 1: fp32 row-major out.
template<int MODE>
__global__ __launch_bounds__(256)
void gemm_bt(const u16* __restrict__ A, const u16* __restrict__ Bt,
             const float* __restrict__ bias, float* __restrict__ Cf,
             u16* __restrict__ Qo, u16* __restrict__ Ko, u16* __restrict__ Vo,
             int N, int K)
{
  __shared__ u16 As[128 * 64];   // linear, unpadded (gload_lds requirement)
  __shared__ u16 Bs[128 * 64];
  const int tid = threadIdx.x;
  const int wave = tid >> 6, lane = tid & 63;
  const int lo = lane & 15, hi = lane >> 4;
  const int wm = (wave >> 1) * 64, wn = (wave & 1) * 64;
  const long bm = (long)blockIdx.y * 128, bn = (long)blockIdx.x * 128;

  f32x4 acc[4][4];
  #pragma unroll
  for (int i = 0; i < 4; i++)
    #pragma unroll
    for (int j = 0; j < 4; j++)
      acc[i][j] = (f32x4){0.f, 0.f, 0.f, 0.f};

  for (int k0 = 0; k0 < K; k0 += 64){
    if (k0) __syncthreads();
    #pragma unroll
    for (int j = 0; j < 4; j++){
      int chunk = j * 256 + tid;
      int row = chunk >> 3, cc = (chunk & 7) * 8;
      GLOAD_LDS(&A [(bm + row) * K + k0 + cc], &As[chunk * 8]);
      GLOAD_LDS(&Bt[(bn + row) * K + k0 + cc], &Bs[chunk * 8]);
    }
    __syncthreads();
    #pragma unroll
    for (int kk = 0; kk < 64; kk += 32){
      short8 af[4], bf[4];
      #pragma unroll
      for (int mi = 0; mi < 4; mi++)
        af[mi] = *reinterpret_cast<const short8*>(&As[(wm + mi*16 + lo) * 64 + kk + hi*8]);
      #pragma unroll
      for (int ni = 0; ni < 4; ni++)
        bf[ni] = *reinterpret_cast<const short8*>(&Bs[(wn + ni*16 + lo) * 64 + kk + hi*8]);
      #pragma unroll
      for (int mi = 0; mi < 4; mi++)
        #pragma unroll
        for (int ni = 0; ni < 4; ni++)
          acc[mi][ni] = __builtin_amdgcn_mfma_f32_16x16x32_bf16(af[mi], bf[ni], acc[mi][ni], 0, 0, 0);
    }
  }

  #pragma unroll
  for (int mi = 0; mi < 4; mi++){
    #pragma unroll
    for (int ni = 0; ni < 4; ni++){
      #pragma unroll
      for (int rg = 0; rg < 4; rg++){
        long rowg = bm + wm + mi*16 + hi*4 + rg;
        long colg = bn + wn + ni*16 + lo;
        float v = acc[mi][ni][rg] + bias[colg];
        if (MODE == 0){
          int part = (int)(colg >> 10), cc = (int)(colg & 1023);
          int h = cc >> 6, d = cc & 63;
          long b = rowg >> 11, t = rowg & 2047;
          if (part == 0) v *= 0.18033688f;   // 0.125 * log2(e): S lands in exp2 domain
          u16* dst = (part == 0) ? Qo : ((part == 1) ? Ko : Vo);
          dst[(((b << 4) + h) * 2048 + t) * 64 + d] = f2bf(v);
        } else {
          Cf[rowg * (long)N + colg] = v;
        }
      }
    }
  }
}

// ---------------- V transpose: [bh][t][d] -> [bh][d][t] ----------------
__global__ __launch_bounds__(256)
void vtrans_kernel(const u16* __restrict__ V, u16* __restrict__ Vt){
  __shared__ u16 Ls[64][72];
  const int bh = blockIdx.y;
  const int t0 = blockIdx.x * 64;
  const u16* Vb = V + ((size_t)bh * 2048 + t0) * 64;
  u16* Ob = Vt + (size_t)bh * 64 * 2048 + t0;
  const int r = threadIdx.x >> 3;        // 0..31
  const int c = (threadIdx.x & 7) * 8;   // 0..56
  #pragma unroll
  for (int rr = 0; rr < 64; rr += 32){
    int row = r + rr;
    *reinterpret_cast<short8*>(&Ls[row][c ^ (((row >> 4) & 3) << 4)]) =
      *reinterpret_cast<const short8*>(&Vb[(size_t)row * 64 + c]);
  }
  __syncthreads();
  const int d  = threadIdx.x >> 2;       // 0..63
  const int tc = (threadIdx.x & 3) * 16; // 0,16,32,48
  const int v  = ((tc >> 4) & 3) << 4;
  short8 o0, o1;
  #pragma unroll
  for (int j = 0; j < 8; j++) o0[j] = (short)Ls[tc + j][d ^ v];
  #pragma unroll
  for (int j = 0; j < 8; j++) o1[j] = (short)Ls[tc + 8 + j][d ^ v];
  *reinterpret_cast<short8*>(&Ob[(size_t)d * 2048 + tc]) = o0;
  *reinterpret_cast<short8*>(&Ob[(size_t)d * 2048 + tc + 8]) = o1;
}

// ---------------- causal flash attention: KVBLK=128, swapped 32x32 MFMA ----
// R10's schedule verbatim (1024 blocks x 256 thr, LPT qg=15-(blk>>6), 8bh/XCD,
// setprio). Loop body processes 128 kv per iteration: 4 QK chains (st0..st3),
// ONE softmax pass over 32 regs (exact online softmax, coarser tiling), two
// T12 packs, 4 PV chains. Only the last 128-tile crosses the diagonal -> mask
// there only; tail reads past diagonal are in-bounds and masked.
// Q,K: [64 bh][2048 t][64 d] bf16 (Q pre-scaled by 0.125*log2e).
// Vt: [64 bh][64 d][2048 t].  Y: [B,T,C] bf16 (head-merged).
__global__ __launch_bounds__(256, 2)
void attn_kernel(const u16* __restrict__ Q, const u16* __restrict__ K,
                 const u16* __restrict__ Vt, u16* __restrict__ Y)
{
  const int blk = blockIdx.x;            // 0..1023
  const int bh = (blk & 7) * 8 + ((blk >> 3) & 7);  // 8 bh per XCD (4MB KV in L2)
  const int qg = 15 - (blk >> 6);        // LPT: longest (qg=15) first
  const int tid = threadIdx.x, wave = tid >> 6, lane = tid & 63;
  const int l31 = lane & 31, h5 = lane >> 5;
  const int qc = qg * 4 + wave;          // 0..63
  const int q0w = qc * 32;
  const int qrow = q0w + l31;            // this lane's q row
  const u16* Qb = Q  + (size_t)bh * 2048 * 64;
  const u16* Kb = K  + (size_t)bh * 2048 * 64;
  const u16* Vb = Vt + (size_t)bh * 64 * 2048;

  // Q^T B-frags: col=q=lane&31, k(d) = ks*16 + h5*8 + j
  short8 qf[4];
  #pragma unroll
  for (int ks = 0; ks < 4; ks++)
    qf[ks] = *reinterpret_cast<const short8*>(&Qb[(size_t)qrow * 64 + ks * 16 + h5 * 8]);

  f32x16 o0, o1;
  #pragma unroll
  for (int i = 0; i < 16; i++){ o0[i] = 0.f; o1[i] = 0.f; }
  float m = -1e30f, l = 0.f;

  const int F = qc >> 1;                 // diagonal 64-tile index
  const int nt128 = (F + 2) >> 1;        // 128-tiles covering kv [0, 64(F+1))

  for (int jt = 0; jt < nt128; jt++){
    const int k0 = jt << 7;

    // ---- K A-frags: 4 kv-blocks of 32; row=kv(lane&31), k(d)=ks*16+h5*8+j ----
    short8 kf0[4], kf1[4], kf2[4], kf3[4];
    #pragma unroll
    for (int ks = 0; ks < 4; ks++){
      const int co = ks * 16 + h5 * 8;
      kf0[ks] = *reinterpret_cast<const short8*>(&Kb[(size_t)(k0      + l31) * 64 + co]);
      kf1[ks] = *reinterpret_cast<const short8*>(&Kb[(size_t)(k0 + 32 + l31) * 64 + co]);
      kf2[ks] = *reinterpret_cast<const short8*>(&Kb[(size_t)(k0 + 64 + l31) * 64 + co]);
      kf3[ks] = *reinterpret_cast<const short8*>(&Kb[(size_t)(k0 + 96 + l31) * 64 + co]);
    }
    // ---- S^T = K . Q^T : col=q, row=kv=(r&3)+8*(r>>2)+4*h5 (+32*n) ----
    f32x16 st0, st1, st2, st3;
    #pragma unroll
    for (int i = 0; i < 16; i++){ st0[i] = 0.f; st1[i] = 0.f; st2[i] = 0.f; st3[i] = 0.f; }
    __builtin_amdgcn_s_setprio(1);
    #pragma unroll
    for (int ks = 0; ks < 4; ks++)
      st0 = __builtin_amdgcn_mfma_f32_32x32x16_bf16(kf0[ks], qf[ks], st0, 0, 0, 0);
    #pragma unroll
    for (int ks = 0; ks < 4; ks++)
      st1 = __builtin_amdgcn_mfma_f32_32x32x16_bf16(kf1[ks], qf[ks], st1, 0, 0, 0);
    #pragma unroll
    for (int ks = 0; ks < 4; ks++)
      st2 = __builtin_amdgcn_mfma_f32_32x32x16_bf16(kf2[ks], qf[ks], st2, 0, 0, 0);
    #pragma unroll
    for (int ks = 0; ks < 4; ks++)
      st3 = __builtin_amdgcn_mfma_f32_32x32x16_bf16(kf3[ks], qf[ks], st3, 0, 0, 0);
    __builtin_amdgcn_s_setprio(0);

    // ---- V^T A-frags, first 64 kv: row=d, k(kv)=ks*16+h5*8+j ----
    short8 va0[4], va1[4];
    #pragma unroll
    for (int ks = 0; ks < 4; ks++){
      const int co = k0 + ks * 16 + h5 * 8;
      va0[ks] = *reinterpret_cast<const short8*>(&Vb[(size_t)l31 * 2048 + co]);
      va1[ks] = *reinterpret_cast<const short8*>(&Vb[(size_t)(32 + l31) * 2048 + co]);
    }

    // ---- causal mask (last 128-tile only) ----
    if (jt == nt128 - 1){
      #pragma unroll
      for (int r = 0; r < 16; r++){
        int kvr = k0 + (r & 3) + 8 * (r >> 2) + 4 * h5;
        if (kvr      > qrow) st0[r] = -1e30f;
        if (kvr + 32 > qrow) st1[r] = -1e30f;
        if (kvr + 64 > qrow) st2[r] = -1e30f;
        if (kvr + 96 > qrow) st3[r] = -1e30f;
      }
    }

    // ---- in-register online softmax over 128 kv (one pass) ----
    float t[16];
    #pragma unroll
    for (int r = 0; r < 16; r++)
      t[r] = fmaxf(fmaxf(st0[r], st1[r]), fmaxf(st2[r], st3[r]));
    #pragma unroll
    for (int s = 8; s > 0; s >>= 1)
      #pragma unroll
      for (int r = 0; r < 8; r++) if (r < s) t[r] = fmaxf(t[r], t[r + s]);
    float rm = fmaxf(t[0], __shfl_xor(t[0], 32));
    float mn = fmaxf(m, rm);
    float alpha = __builtin_amdgcn_exp2f(m - mn);
    m = mn;
    float rs = 0.f;
    #pragma unroll
    for (int r = 0; r < 16; r++){
      st0[r] = __builtin_amdgcn_exp2f(st0[r] - mn);
      st1[r] = __builtin_amdgcn_exp2f(st1[r] - mn);
      st2[r] = __builtin_amdgcn_exp2f(st2[r] - mn);
      st3[r] = __builtin_amdgcn_exp2f(st3[r] - mn);
      rs += (st0[r] + st1[r]) + (st2[r] + st3[r]);
    }
    rs += __shfl_xor(rs, 32);
    l = l * alpha + rs;
    #pragma unroll
    for (int i = 0; i < 16; i++){ o0[i] *= alpha; o1[i] *= alpha; }

    // ---- pack P^T B-frags (T12 exchange): paA from st0/st1, paB from st2/st3 ----
    short8 paA[4], paB[4];
    #pragma unroll
    for (int ks2 = 0; ks2 < 4; ks2++){
      const f32x16& sv = (ks2 < 2) ? st0 : st1;
      const int gg = 8 * (ks2 & 1);
      u32 w0 = cvtpk(sv[gg + 0], sv[gg + 1]);
      u32 w1 = cvtpk(sv[gg + 2], sv[gg + 3]);
      u32 w2 = cvtpk(sv[gg + 4], sv[gg + 5]);
      u32 w3 = cvtpk(sv[gg + 6], sv[gg + 7]);
      u32 sa = h5 ? w0 : w2;
      u32 sb = h5 ? w1 : w3;
      u32 ra = (u32)__shfl_xor((int)sa, 32);
      u32 rb = (u32)__shfl_xor((int)sb, 32);
      u32x4 pw;
      pw.x = h5 ? ra : w0;
      pw.y = h5 ? rb : w1;
      pw.z = h5 ? w2 : ra;
      pw.w = h5 ? w3 : rb;
      paA[ks2] = __builtin_bit_cast(short8, pw);
    }
    #pragma unroll
    for (int ks2 = 0; ks2 < 4; ks2++){
      const f32x16& sv = (ks2 < 2) ? st2 : st3;
      const int gg = 8 * (ks2 & 1);
      u32 w0 = cvtpk(sv[gg + 0], sv[gg + 1]);
      u32 w1 = cvtpk(sv[gg + 2], sv[gg + 3]);
      u32 w2 = cvtpk(sv[gg + 4], sv[gg + 5]);
      u32 w3 = cvtpk(sv[gg + 6], sv[gg + 7]);
      u32 sa = h5 ? w0 : w2;
      u32 sb = h5 ? w1 : w3;
      u32 ra = (u32)__shfl_xor((int)sa, 32);
      u32 rb = (u32)__shfl_xor((int)sb, 32);
      u32x4 pw;
      pw.x = h5 ? ra : w0;
      pw.y = h5 ? rb : w1;
      pw.z = h5 ? w2 : ra;
      pw.w = h5 ? w3 : rb;
      paB[ks2] = __builtin_bit_cast(short8, pw);
    }

    // ---- V^T A-frags, second 64 kv ----
    short8 vb0[4], vb1[4];
    #pragma unroll
    for (int ks = 0; ks < 4; ks++){
      const int co = k0 + 64 + ks * 16 + h5 * 8;
      vb0[ks] = *reinterpret_cast<const short8*>(&Vb[(size_t)l31 * 2048 + co]);
      vb1[ks] = *reinterpret_cast<const short8*>(&Vb[(size_t)(32 + l31) * 2048 + co]);
    }

    // ---- O^T += V^T . P^T  (kv slots 0..63 then 64..127) ----
    __builtin_amdgcn_s_setprio(1);
    #pragma unroll
    for (int ks = 0; ks < 4; ks++)
      o0 = __builtin_amdgcn_mfma_f32_32x32x16_bf16(va0[ks], paA[ks], o0, 0, 0, 0);
    #pragma unroll
    for (int ks = 0; ks < 4; ks++)
      o1 = __builtin_amdgcn_mfma_f32_32x32x16_bf16(va1[ks], paA[ks], o1, 0, 0, 0);
    #pragma unroll
    for (int ks = 0; ks < 4; ks++)
      o0 = __builtin_amdgcn_mfma_f32_32x32x16_bf16(vb0[ks], paB[ks], o0, 0, 0, 0);
    #pragma unroll
    for (int ks = 0; ks < 4; ks++)
      o1 = __builtin_amdgcn_mfma_f32_32x32x16_bf16(vb1[ks], paB[ks], o1, 0, 0, 0);
    __builtin_amdgcn_s_setprio(0);
  }

  // ---- epilogue: O^T lane holds col q=l31, rows d = (r&3)+8*(r>>2)+4*h5 (+32) ----
  const int b = bh >> 4, h = bh & 15;
  const float inv = 1.f / l;
  u16* Yr = Y + ((size_t)(b * 2048 + qrow)) * 1024 + h * 64;
  #pragma unroll
  for (int rq = 0; rq < 4; rq++){
    ushort4 ua, ub;
    #pragma unroll
    for (int e = 0; e < 4; e++){
      ((u16*)&ua)[e] = f2bf(o0[rq * 4 + e] * inv);
      ((u16*)&ub)[e] = f2bf(o1[rq * 4 + e] * inv);
    }
    *reinterpret_cast<ushort4*>(&Yr[rq * 8 + h5 * 4])      = ua;
    *reinterpret_cast<ushort4*>(&Yr[32 + rq * 8 + h5 * 4]) = ub;
  }
}

// ---------------- launch ----------------
extern "C" void kernel_launch(void* const* d_in, const int* in_sizes, int n_in,
                              void* d_out, int out_size, void* d_ws, size_t ws_size,
                              hipStream_t stream)
{
  const float* x      = (const float*)d_in[0];
  const float* w_qkv  = (const float*)d_in[1];
  const float* b_qkv  = (const float*)d_in[2];
  const float* w_proj = (const float*)d_in[3];
  const float* b_proj = (const float*)d_in[4];
  float* out = (float*)d_out;

  char* ws = (char*)d_ws;
  u16* xb     = (u16*)(ws);                       // 16 MB  [8192,1024]  (reused as vtb)
  u16* wqkvb  = (u16*)(ws + (16u << 20));         //  6 MB  [3072,1024]
  u16* wprojb = (u16*)(ws + (22u << 20));         //  2 MB  [1024,1024]
  u16* qb     = (u16*)(ws + (24u << 20));         // 16 MB  [64,2048,64]
  u16* kb     = (u16*)(ws + (40u << 20));         // 16 MB
  u16* vb     = (u16*)(ws + (56u << 20));         // 16 MB
  u16* yb     = (u16*)(ws + (72u << 20));         // 16 MB  [8192,1024]
  u16* vtb    = xb;                               // 16 MB  [64,64,2048] (after GEMM1, xb is dead)

  int nx  = B_ * T_ * C_ / 4;         // 2097152
  int nw1 = 3 * C_ * C_ / 4;          //  786432
  int nw2 = C_ * C_ / 4;              //  262144
  cvt_kernel<<<(nx  + 255) / 256, 256, 0, stream>>>(x,      xb,     nx);
  cvt_kernel<<<(nw1 + 255) / 256, 256, 0, stream>>>(w_qkv,  wqkvb,  nw1);
  cvt_kernel<<<(nw2 + 255) / 256, 256, 0, stream>>>(w_proj, wprojb, nw2);

  dim3 g1(3072 / 128, M_ / 128);
  gemm_bt<0><<<g1, 256, 0, stream>>>(xb, wqkvb, b_qkv, nullptr, qb, kb, vb, 3072, C_);

  dim3 gt(T_ / 64, B_ * H_);
  vtrans_kernel<<<gt, 256, 0, stream>>>(vb, vtb);

  attn_kernel<<<1024, 256, 0, stream>>>(qb, kb, vtb, yb);

  dim3 g2(1024 / 128, M_ / 128);
  gemm_bt<1><<<g2, 256, 0, stream>>>(yb, wprojb, b_proj, out, nullptr, nullptr, nullptr, C_, C_);
}

// Round 15
// 259.853 us; speedup vs baseline: 1.2023x; 1.0319x over previous
//
#include <hip/hip_runtime.h>
#include <hip/hip_bf16.h>

#define B_ 4
#define T_ 2048
#define C_ 1024
#define H_ 16
#define HD_ 64
#define M_ (B_*T_)   // 8192

typedef __attribute__((ext_vector_type(8))) short short8;
typedef __attribute__((ext_vector_type(4))) float f32x4;
typedef __attribute__((ext_vector_type(16))) float f32x16;
typedef __attribute__((ext_vector_type(4))) unsigned int u32x4;
typedef unsigned short u16;
typedef unsigned int u32;

__device__ __forceinline__ u16 f2bf(float f){
  unsigned int x = __builtin_bit_cast(unsigned int, f);
  x += 0x7fffu + ((x >> 16) & 1u);   // RNE
  return (u16)(x >> 16);
}

__device__ __forceinline__ u32 cvtpk(float lo, float hi){
  u32 r;
  asm("v_cvt_pk_bf16_f32 %0, %1, %2" : "=v"(r) : "v"(lo), "v"(hi));
  return r;
}

// async global->LDS, 16B per lane; LDS dest must be wave-uniform base + lane*16
#define GLOAD_LDS(gsrc, ldst) \
  __builtin_amdgcn_global_load_lds((const __attribute__((address_space(1))) u32*)(gsrc), \
                                   (__attribute__((address_space(3))) u32*)(ldst), 16, 0, 0)

// ---------------- fused fp32 -> bf16 convert (x, w_qkv, w_proj in one grid) ----
// float4 counts: nx=2097152, nw1=786432, nw2=262144; total 3145728 = 12288 blocks.
__global__ __launch_bounds__(256)
void cvt3_kernel(const float* __restrict__ x, const float* __restrict__ w1,
                 const float* __restrict__ w2, u16* __restrict__ xb,
                 u16* __restrict__ w1b, u16* __restrict__ w2b){
  int i = blockIdx.x * 256 + threadIdx.x;
  const float* src; u16* dst; int off;
  if (i < 2097152)              { src = x;  dst = xb;  off = i; }
  else if (i < 2097152 + 786432){ src = w1; dst = w1b; off = i - 2097152; }
  else                          { src = w2; dst = w2b; off = i - (2097152 + 786432); }
  float4 f = reinterpret_cast<const float4*>(src)[off];
  ushort4 u;
  u.x = f2bf(f.x); u.y = f2bf(f.y); u.z = f2bf(f.z); u.w = f2bf(f.w);
  reinterpret_cast<ushort4*>(dst)[off] = u;
}

// ---------------- GEMM: C[M,N] = A[M,K] * Bt[N,K]^T + bias ----------------
// m97-structure: linear [128][64] LDS tiles staged via global_load_lds width=16.
// T1 XCD-chunked bijective swizzle on the flat block id (nwg % 8 == 0 for both
// launches): each XCD gets a contiguous chunk -> A panels become L2-resident.
// MODE 0: scatter-epilogue into q/k/v [B,H,T,HD] bf16 (Q pre-scaled by 0.125*log2e).
// MODE 1: fp32 row-major out.
template<int MODE>
__global__ __launch_bounds__(256)
void gemm_bt(const u16* __restrict__ A, const u16* __restrict__ Bt,
             const float* __restrict__ bias, float* __restrict__ Cf,
             u16* __restrict__ Qo, u16* __restrict__ Ko, u16* __restrict__ Vo,
             int N, int K)
{
  __shared__ u16 As[128 * 64];   // linear, unpadded (gload_lds requirement)
  __shared__ u16 Bs[128 * 64];
  const int tid = threadIdx.x;
  const int wave = tid >> 6, lane = tid & 63;
  const int lo = lane & 15, hi = lane >> 4;
  const int wm = (wave >> 1) * 64, wn = (wave & 1) * 64;

  const int nwgx = gridDim.x;
  const int nwg  = gridDim.x * gridDim.y;
  const int flat = blockIdx.y * nwgx + blockIdx.x;
  const int cpx  = nwg >> 3;                       // nwg % 8 == 0
  const int swz  = (flat & 7) * cpx + (flat >> 3); // bijective XCD-chunk remap
  const long bm = (long)(swz / nwgx) * 128, bn = (long)(swz % nwgx) * 128;

  f32x4 acc[4][4];
  #pragma unroll
  for (int i = 0; i < 4; i++)
    #pragma unroll
    for (int j = 0; j < 4; j++)
      acc[i][j] = (f32x4){0.f, 0.f, 0.f, 0.f};

  for (int k0 = 0; k0 < K; k0 += 64){
    if (k0) __syncthreads();
    #pragma unroll
    for (int j = 0; j < 4; j++){
      int chunk = j * 256 + tid;
      int row = chunk >> 3, cc = (chunk & 7) * 8;
      GLOAD_LDS(&A [(bm + row) * K + k0 + cc], &As[chunk * 8]);
      GLOAD_LDS(&Bt[(bn + row) * K + k0 + cc], &Bs[chunk * 8]);
    }
    __syncthreads();
    #pragma unroll
    for (int kk = 0; kk < 64; kk += 32){
      short8 af[4], bf[4];
      #pragma unroll
      for (int mi = 0; mi < 4; mi++)
        af[mi] = *reinterpret_cast<const short8*>(&As[(wm + mi*16 + lo) * 64 + kk + hi*8]);
      #pragma unroll
      for (int ni = 0; ni < 4; ni++)
        bf[ni] = *reinterpret_cast<const short8*>(&Bs[(wn + ni*16 + lo) * 64 + kk + hi*8]);
      #pragma unroll
      for (int mi = 0; mi < 4; mi++)
        #pragma unroll
        for (int ni = 0; ni < 4; ni++)
          acc[mi][ni] = __builtin_amdgcn_mfma_f32_16x16x32_bf16(af[mi], bf[ni], acc[mi][ni], 0, 0, 0);
    }
  }

  #pragma unroll
  for (int mi = 0; mi < 4; mi++){
    #pragma unroll
    for (int ni = 0; ni < 4; ni++){
      #pragma unroll
      for (int rg = 0; rg < 4; rg++){
        long rowg = bm + wm + mi*16 + hi*4 + rg;
        long colg = bn + wn + ni*16 + lo;
        float v = acc[mi][ni][rg] + bias[colg];
        if (MODE == 0){
          int part = (int)(colg >> 10), cc = (int)(colg & 1023);
          int h = cc >> 6, d = cc & 63;
          long b = rowg >> 11, t = rowg & 2047;
          if (part == 0) v *= 0.18033688f;   // 0.125 * log2(e): S lands in exp2 domain
          u16* dst = (part == 0) ? Qo : ((part == 1) ? Ko : Vo);
          dst[(((b << 4) + h) * 2048 + t) * 64 + d] = f2bf(v);
        } else {
          Cf[rowg * (long)N + colg] = v;
        }
      }
    }
  }
}

// ---------------- V transpose: [bh][t][d] -> [bh][d][t] ----------------
__global__ __launch_bounds__(256)
void vtrans_kernel(const u16* __restrict__ V, u16* __restrict__ Vt){
  __shared__ u16 Ls[64][72];
  const int bh = blockIdx.y;
  const int t0 = blockIdx.x * 64;
  const u16* Vb = V + ((size_t)bh * 2048 + t0) * 64;
  u16* Ob = Vt + (size_t)bh * 64 * 2048 + t0;
  const int r = threadIdx.x >> 3;        // 0..31
  const int c = (threadIdx.x & 7) * 8;   // 0..56
  #pragma unroll
  for (int rr = 0; rr < 64; rr += 32){
    int row = r + rr;
    *reinterpret_cast<short8*>(&Ls[row][c ^ (((row >> 4) & 3) << 4)]) =
      *reinterpret_cast<const short8*>(&Vb[(size_t)row * 64 + c]);
  }
  __syncthreads();
  const int d  = threadIdx.x >> 2;       // 0..63
  const int tc = (threadIdx.x & 3) * 16; // 0,16,32,48
  const int v  = ((tc >> 4) & 3) << 4;
  short8 o0, o1;
  #pragma unroll
  for (int j = 0; j < 8; j++) o0[j] = (short)Ls[tc + j][d ^ v];
  #pragma unroll
  for (int j = 0; j < 8; j++) o1[j] = (short)Ls[tc + 8 + j][d ^ v];
  *reinterpret_cast<short8*>(&Ob[(size_t)d * 2048 + tc]) = o0;
  *reinterpret_cast<short8*>(&Ob[(size_t)d * 2048 + tc + 8]) = o1;
}

// ---------------- causal flash attention: swapped 32x32 MFMA, in-reg softmax ----
// R10 kernel VERBATIM (best measured: 140.8 us, passed twice). LPT order
// qg = 15-(blk>>6); T5 setprio around MFMA clusters; KVBLK=64; VGPR 72.
// Q,K: [64 bh][2048 t][64 d] bf16 (Q pre-scaled by 0.125*log2e).
// Vt: [64 bh][64 d][2048 t].  Y: [B,T,C] bf16 (head-merged).
__global__ __launch_bounds__(256, 2)
void attn_kernel(const u16* __restrict__ Q, const u16* __restrict__ K,
                 const u16* __restrict__ Vt, u16* __restrict__ Y)
{
  const int blk = blockIdx.x;            // 0..1023
  const int bh = (blk & 7) * 8 + ((blk >> 3) & 7);  // 8 bh per XCD (4MB KV in L2)
  const int qg = 15 - (blk >> 6);        // LPT: longest (qg=15) first
  const int tid = threadIdx.x, wave = tid >> 6, lane = tid & 63;
  const int l31 = lane & 31, h5 = lane >> 5;
  const int qc = qg * 4 + wave;          // 0..63
  const int q0w = qc * 32;
  const int qrow = q0w + l31;            // this lane's q row
  const u16* Qb = Q  + (size_t)bh * 2048 * 64;
  const u16* Kb = K  + (size_t)bh * 2048 * 64;
  const u16* Vb = Vt + (size_t)bh * 64 * 2048;

  // Q^T B-frags: col=q=lane&31, k(d) = ks*16 + h5*8 + j
  short8 qf[4];
  #pragma unroll
  for (int ks = 0; ks < 4; ks++)
    qf[ks] = *reinterpret_cast<const short8*>(&Qb[(size_t)qrow * 64 + ks * 16 + h5 * 8]);

  f32x16 o0, o1;
  #pragma unroll
  for (int i = 0; i < 16; i++){ o0[i] = 0.f; o1[i] = 0.f; }
  float m = -1e30f, l = 0.f;

  const int F = qc >> 1;                 // diagonal tile index

  for (int jt = 0; jt <= F; jt++){
    const int k0 = jt << 6;

    // ---- K A-frags: row=kv(lane&31), k(d)=ks*16+h5*8+j ; 2 kv-blocks of 32 ----
    short8 kf0[4], kf1[4];
    #pragma unroll
    for (int ks = 0; ks < 4; ks++){
      kf0[ks] = *reinterpret_cast<const short8*>(&Kb[(size_t)(k0 + l31) * 64 + ks * 16 + h5 * 8]);
      kf1[ks] = *reinterpret_cast<const short8*>(&Kb[(size_t)(k0 + 32 + l31) * 64 + ks * 16 + h5 * 8]);
    }
    // ---- S^T = K . Q^T : col=q, row=kv=(r&3)+8*(r>>2)+4*h5 (+32*n) ----
    f32x16 st0, st1;
    #pragma unroll
    for (int i = 0; i < 16; i++){ st0[i] = 0.f; st1[i] = 0.f; }
    __builtin_amdgcn_s_setprio(1);
    #pragma unroll
    for (int ks = 0; ks < 4; ks++)
      st0 = __builtin_amdgcn_mfma_f32_32x32x16_bf16(kf0[ks], qf[ks], st0, 0, 0, 0);
    #pragma unroll
    for (int ks = 0; ks < 4; ks++)
      st1 = __builtin_amdgcn_mfma_f32_32x32x16_bf16(kf1[ks], qf[ks], st1, 0, 0, 0);
    __builtin_amdgcn_s_setprio(0);

    // ---- V^T A-frags issued early: row=d, k(kv)=ks*16+h5*8+j ----
    short8 vf0[4], vf1[4];
    #pragma unroll
    for (int ks = 0; ks < 4; ks++){
      vf0[ks] = *reinterpret_cast<const short8*>(&Vb[(size_t)l31 * 2048 + k0 + ks * 16 + h5 * 8]);
      vf1[ks] = *reinterpret_cast<const short8*>(&Vb[(size_t)(32 + l31) * 2048 + k0 + ks * 16 + h5 * 8]);
    }

    // ---- causal mask (diagonal tile only) ----
    if (jt == F){
      #pragma unroll
      for (int r = 0; r < 16; r++){
        int kvr = k0 + (r & 3) + 8 * (r >> 2) + 4 * h5;
        if (kvr > qrow)      st0[r] = -1e30f;
        if (kvr + 32 > qrow) st1[r] = -1e30f;
      }
    }

    // ---- in-register online softmax (one q-row per lane), rescale every tile ----
    float t[16];
    #pragma unroll
    for (int r = 0; r < 16; r++) t[r] = fmaxf(st0[r], st1[r]);
    #pragma unroll
    for (int s = 8; s > 0; s >>= 1)
      #pragma unroll
      for (int r = 0; r < 8; r++) if (r < s) t[r] = fmaxf(t[r], t[r + s]);
    float rm = fmaxf(t[0], __shfl_xor(t[0], 32));
    float mn = fmaxf(m, rm);
    float alpha = __builtin_amdgcn_exp2f(m - mn);
    m = mn;
    float rs = 0.f;
    #pragma unroll
    for (int r = 0; r < 16; r++){
      st0[r] = __builtin_amdgcn_exp2f(st0[r] - mn);
      st1[r] = __builtin_amdgcn_exp2f(st1[r] - mn);
      rs += st0[r] + st1[r];
    }
    rs += __shfl_xor(rs, 32);
    l = l * alpha + rs;
    #pragma unroll
    for (int i = 0; i < 16; i++){ o0[i] *= alpha; o1[i] *= alpha; }

    // ---- pack P^T B-frags: pa[ks2][e] = P[q][ks2*16 + h5*8 + e] (T12 exchange) ----
    short8 pa[4];
    #pragma unroll
    for (int ks2 = 0; ks2 < 4; ks2++){
      const f32x16& sv = (ks2 < 2) ? st0 : st1;
      const int gg = 8 * (ks2 & 1);
      u32 w0 = cvtpk(sv[gg + 0], sv[gg + 1]);
      u32 w1 = cvtpk(sv[gg + 2], sv[gg + 3]);
      u32 w2 = cvtpk(sv[gg + 4], sv[gg + 5]);
      u32 w3 = cvtpk(sv[gg + 6], sv[gg + 7]);
      u32 sa = h5 ? w0 : w2;               // send partner what it needs
      u32 sb = h5 ? w1 : w3;
      u32 ra = (u32)__shfl_xor((int)sa, 32);
      u32 rb = (u32)__shfl_xor((int)sb, 32);
      u32x4 pw;
      pw.x = h5 ? ra : w0;
      pw.y = h5 ? rb : w1;
      pw.z = h5 ? w2 : ra;
      pw.w = h5 ? w3 : rb;
      pa[ks2] = __builtin_bit_cast(short8, pw);
    }

    // ---- O^T += V^T . P^T ----
    __builtin_amdgcn_s_setprio(1);
    #pragma unroll
    for (int ks = 0; ks < 4; ks++)
      o0 = __builtin_amdgcn_mfma_f32_32x32x16_bf16(vf0[ks], pa[ks], o0, 0, 0, 0);
    #pragma unroll
    for (int ks = 0; ks < 4; ks++)
      o1 = __builtin_amdgcn_mfma_f32_32x32x16_bf16(vf1[ks], pa[ks], o1, 0, 0, 0);
    __builtin_amdgcn_s_setprio(0);
  }

  // ---- epilogue: O^T lane holds col q=l31, rows d = (r&3)+8*(r>>2)+4*h5 (+32) ----
  const int b = bh >> 4, h = bh & 15;
  const float inv = 1.f / l;
  u16* Yr = Y + ((size_t)(b * 2048 + qrow)) * 1024 + h * 64;
  #pragma unroll
  for (int rq = 0; rq < 4; rq++){
    ushort4 ua, ub;
    #pragma unroll
    for (int e = 0; e < 4; e++){
      ((u16*)&ua)[e] = f2bf(o0[rq * 4 + e] * inv);
      ((u16*)&ub)[e] = f2bf(o1[rq * 4 + e] * inv);
    }
    *reinterpret_cast<ushort4*>(&Yr[rq * 8 + h5 * 4])      = ua;
    *reinterpret_cast<ushort4*>(&Yr[32 + rq * 8 + h5 * 4]) = ub;
  }
}

// ---------------- launch ----------------
extern "C" void kernel_launch(void* const* d_in, const int* in_sizes, int n_in,
                              void* d_out, int out_size, void* d_ws, size_t ws_size,
                              hipStream_t stream)
{
  const float* x      = (const float*)d_in[0];
  const float* w_qkv  = (const float*)d_in[1];
  const float* b_qkv  = (const float*)d_in[2];
  const float* w_proj = (const float*)d_in[3];
  const float* b_proj = (const float*)d_in[4];
  float* out = (float*)d_out;

  char* ws = (char*)d_ws;
  u16* xb     = (u16*)(ws);                       // 16 MB  [8192,1024]  (reused as vtb)
  u16* wqkvb  = (u16*)(ws + (16u << 20));         //  6 MB  [3072,1024]
  u16* wprojb = (u16*)(ws + (22u << 20));         //  2 MB  [1024,1024]
  u16* qb     = (u16*)(ws + (24u << 20));         // 16 MB  [64,2048,64]
  u16* kb     = (u16*)(ws + (40u << 20));         // 16 MB
  u16* vb     = (u16*)(ws + (56u << 20));         // 16 MB
  u16* yb     = (u16*)(ws + (72u << 20));         // 16 MB  [8192,1024]
  u16* vtb    = xb;                               // 16 MB  [64,64,2048] (after GEMM1, xb is dead)

  // fused converts: 12288 blocks cover x (2097152) + w_qkv (786432) + w_proj (262144) float4s
  cvt3_kernel<<<12288, 256, 0, stream>>>(x, w_qkv, w_proj, xb, wqkvb, wprojb);

  dim3 g1(3072 / 128, M_ / 128);
  gemm_bt<0><<<g1, 256, 0, stream>>>(xb, wqkvb, b_qkv, nullptr, qb, kb, vb, 3072, C_);

  dim3 gt(T_ / 64, B_ * H_);
  vtrans_kernel<<<gt, 256, 0, stream>>>(vb, vtb);

  attn_kernel<<<1024, 256, 0, stream>>>(qb, kb, vtb, yb);

  dim3 g2(1024 / 128, M_ / 128);
  gemm_bt<1><<<g2, 256, 0, stream>>>(yb, wprojb, b_proj, out, nullptr, nullptr, nullptr, C_, C_);
}